// Round 1
// baseline (575.916 us; speedup 1.0000x reference)
//
#include <hip/hip_runtime.h>
#include <math.h>

#define NJ 17
#define CPJ 8
#define NBATCH 8
#define NSP 1728
#define NC 136
#define WA_OFF 1880064  // offset of A copy inside ws (floats)

__device__ const int d_CA[16] = {0,1,2,5,4,3,6,7,8,9,8,11,10,8,13,14};
__device__ const int d_CB[16] = {1,2,6,4,3,6,7,8,16,16,12,12,11,13,14,15};
__device__ const int d_Gcnt[17] = {1,2,2,2,2,1,3,2,4,1,1,2,2,2,2,1,2};
__device__ const int d_Gj1[17][4] = {
  {1,0,0,0},{0,2,0,0},{1,6,0,0},{4,6,0,0},{5,3,0,0},{4,0,0,0},{2,3,7,0},{6,8,0,0},
  {7,16,12,13},{16,0,0,0},{11,0,0,0},{12,10,0,0},{8,11,0,0},{8,14,0,0},{13,15,0,0},
  {14,0,0,0},{8,9,0,0}};
__device__ const int d_Glim[17][4] = {
  {0,0,0,0},{0,1,0,0},{1,2,0,0},{4,5,0,0},{3,4,0,0},{3,0,0,0},{2,5,6,0},{6,7,0,0},
  {7,8,10,13},{9,0,0,0},{12,0,0,0},{11,12,0,0},{10,11,0,0},{13,14,0,0},{14,15,0,0},
  {15,0,0,0},{8,9,0,0}};
__device__ const int d_Ge[17][4] = {
  {1,0,0,0},{0,1,0,0},{0,1,0,0},{0,1,0,0},{0,1,0,0},{1,0,0,0},{0,0,1,0},{0,1,0,0},
  {0,1,1,1},{1,0,0,0},{1,0,0,0},{1,0,0,0},{0,0,0,0},{0,1,0,0},{0,1,0,0},
  {0,0,0,0},{0,0,0,0}};

// ---------------- K1: per (b,j) attention softmax, weighted, shared ----------------
__global__ __launch_bounds__(256) void k1(
    const float* __restrict__ x, const float* __restrict__ w_pi, const float* __restrict__ w_att,
    float* __restrict__ A_out, float* __restrict__ A_ws,
    float* __restrict__ weighted, float* __restrict__ shared_ws)
{
  __shared__ __attribute__((aligned(16))) float s_lds[NSP];
  __shared__ float wpis[64];
  __shared__ float redA[4], redB[4];
  __shared__ float shred[4][8];
  const int tid = threadIdx.x, lane = tid & 63, wid = tid >> 6;
  const int j = blockIdx.x, b = blockIdx.y;
  if (tid < 64) wpis[tid] = w_pi[j * 64 + tid];
  float wa[8];
#pragma unroll
  for (int c = 0; c < 8; c++) wa[c] = w_att[j * 8 + c];
  __syncthreads();
  const float* xb = x + (size_t)(b * NC + j * 8) * NSP;
  float lmax = -1e30f;
  for (int it = 0; it < 7; ++it) {
    int n = it * 256 + tid;
    if (n < NSP) {
      float s = 0.f;
#pragma unroll
      for (int c = 0; c < 8; c++) s = fmaf(wa[c], xb[c * NSP + n], s);
      s_lds[n] = s;
      lmax = fmaxf(lmax, s);
    }
  }
#pragma unroll
  for (int off = 32; off >= 1; off >>= 1) lmax = fmaxf(lmax, __shfl_xor(lmax, off));
  if (lane == 0) redA[wid] = lmax;
  __syncthreads();
  const float M = fmaxf(fmaxf(redA[0], redA[1]), fmaxf(redA[2], redA[3]));
  float lsum = 0.f;
  for (int it = 0; it < 7; ++it) {
    int n = it * 256 + tid;
    if (n < NSP) { float e = __expf(s_lds[n] - M); s_lds[n] = e; lsum += e; }
  }
#pragma unroll
  for (int off = 32; off >= 1; off >>= 1) lsum += __shfl_xor(lsum, off);
  if (lane == 0) redB[wid] = lsum;
  __syncthreads();
  const float inv = 1.0f / (redB[0] + redB[1] + redB[2] + redB[3]);
  float sh[8];
#pragma unroll
  for (int o = 0; o < 8; o++) sh[o] = 0.f;
  const int aoff = (b * NJ + j) * NSP;
  for (int it = 0; it < 7; ++it) {
    int n = it * 256 + tid;
    if (n < NSP) {
      float a = s_lds[n] * inv;
      A_out[aoff + n] = a;
      A_ws[aoff + n] = a;
      float xv[8];
#pragma unroll
      for (int c = 0; c < 8; c++) xv[c] = xb[c * NSP + n];
#pragma unroll
      for (int o = 0; o < 8; o++) {
        float pi = 0.f;
#pragma unroll
        for (int c = 0; c < 8; c++) pi = fmaf(wpis[o * 8 + c], xv[c], pi);
        float w = pi * a;
        weighted[(size_t)((b * NJ + j) * 8 + o) * NSP + n] = w;
        sh[o] += w;
      }
    }
  }
#pragma unroll
  for (int o = 0; o < 8; o++) {
    float v = sh[o];
#pragma unroll
    for (int off = 32; off >= 1; off >>= 1) v += __shfl_xor(v, off);
    if (lane == 0) shred[wid][o] = v;
  }
  __syncthreads();
  if (tid < 8)
    shared_ws[b * NC + j * 8 + tid] = shred[0][tid] + shred[1][tid] + shred[2][tid] + shred[3][tid];
}

// ---------------- K2a: per (l,m) row max of mask logits ----------------
__global__ __launch_bounds__(256) void k2a(
    const float* __restrict__ limb_mean, const float* __restrict__ limb_std,
    float* __restrict__ mmax_ws)
{
  const float SPf = 2500.0f / 11.0f;
  const int tid = threadIdx.x, lane = tid & 63, wid = tid >> 6;
  const int row = blockIdx.x * 4 + wid;       // 6912 blocks * 4 rows = 27648
  const int l = row / NSP, m = row - l * NSP;
  const float mean = limb_mean[l], sd = limb_std[l];
  const float invd = 1.0f / (20.0f * sd * sd + 0.1f);
  int imx = m / 144, rem = m - imx * 144, imy = rem / 12, imz = rem - imy * 12;
  const float fmx = (float)imx, fmy = (float)imy, fmz = (float)imz;
  float lmax = -1e30f;
  for (int k = 0; k < 27; k++) {
    int n = k * 64 + lane;
    int inx = n / 144, nrem = n - inx * 144, iny = nrem / 12, inz = nrem - iny * 12;
    float dx = fmx - (float)inx, dy = fmy - (float)iny, dz = fmz - (float)inz;
    float d2 = fmaf(dx, dx, fmaf(dy, dy, dz * dz));
    float t = fmaf(SPf, sqrtf(d2), -mean);
    float lg = -(t * invd) * t;
    lmax = fmaxf(lmax, lg);
  }
#pragma unroll
  for (int off = 32; off >= 1; off >>= 1) lmax = fmaxf(lmax, __shfl_xor(lmax, off));
  if (lane == 0) mmax_ws[row] = lmax;
}

// ---------------- K2b: fused P-gen + GEMM + den-divide -> feat ----------------
__global__ __launch_bounds__(256) void k2b(
    const float* __restrict__ limb_mean, const float* __restrict__ limb_std,
    const float* __restrict__ ws_base, const float* __restrict__ mmax_ws,
    float* __restrict__ feat)
{
  const float SPf = 2500.0f / 11.0f;
  __shared__ __attribute__((aligned(16))) float Bs[144 * 68];
  __shared__ __attribute__((aligned(16))) float Ps[64 * 68];
  __shared__ float den_s[16 * 64];
  __shared__ int rowbase[144];
  __shared__ float mposx[64], mposy[64], mposz[64], mmax_s[64];

  const int tid = threadIdx.x;
  const int l = blockIdx.y;
  const int m0 = blockIdx.x * 64;
  const int tm = tid & 15;
  const int tc = tid >> 4;

  if (tid < 144) {
    int b = tid / 18, s = tid - b * 18;
    int ja = d_CA[l], jb = d_CB[l];
    int off;
    if (s < 8)        off = ((b * NJ + ja) * CPJ + s) * NSP;
    else if (s < 16)  off = ((b * NJ + jb) * CPJ + (s - 8)) * NSP;
    else if (s == 16) off = WA_OFF + (b * NJ + ja) * NSP;
    else              off = WA_OFF + (b * NJ + jb) * NSP;
    rowbase[tid] = off;
  }
  if (tid < 64) {
    int m = m0 + tid;
    int imx = m / 144, rem = m - imx * 144, imy = rem / 12, imz = rem - imy * 12;
    mposx[tid] = (float)imx; mposy[tid] = (float)imy; mposz[tid] = (float)imz;
    mmax_s[tid] = mmax_ws[l * NSP + m];
  }
  const float mean = limb_mean[l];
  const float sd = limb_std[l];
  const float invd = 1.0f / (20.0f * sd * sd + 0.1f);

  float acc[4][9];
#pragma unroll
  for (int i = 0; i < 4; i++)
#pragma unroll
    for (int k = 0; k < 9; k++) acc[i][k] = 0.f;

  __syncthreads();

  const int nn = tid & 63;
  const int mb = tid >> 6;

  for (int nt = 0; nt < 27; ++nt) {
    const int n0 = nt * 64;
    // stage B tile (144 x 64)
#pragma unroll
    for (int k = 0; k < 9; ++k) {
      int idx = tid + 256 * k;
      int row = idx >> 4, off4 = (idx & 15) * 4;
      const float4 v = *reinterpret_cast<const float4*>(ws_base + rowbase[row] + n0 + off4);
      *reinterpret_cast<float4*>(&Bs[row * 68 + off4]) = v;
    }
    // generate P tile (64 x 64)
    {
      int n = n0 + nn;
      int inx = n / 144, nrem = n - inx * 144, iny = nrem / 12, inz = nrem - iny * 12;
      float fnx = (float)inx, fny = (float)iny, fnz = (float)inz;
#pragma unroll
      for (int mi = 0; mi < 16; ++mi) {
        int ml = mb + 4 * mi;
        float dx = mposx[ml] - fnx, dy = mposy[ml] - fny, dz = mposz[ml] - fnz;
        float d2 = fmaf(dx, dx, fmaf(dy, dy, dz * dz));
        float t = fmaf(SPf, sqrtf(d2), -mean);
        float arg = fmaf(-t * invd, t, -mmax_s[ml]);
        Ps[ml * 68 + nn] = __expf(arg);
      }
    }
    __syncthreads();
    // FMA phase
#pragma unroll 4
    for (int n4 = 0; n4 < 16; ++n4) {
      float4 p[4];
#pragma unroll
      for (int i = 0; i < 4; i++)
        p[i] = *reinterpret_cast<const float4*>(&Ps[(tm + 16 * i) * 68 + n4 * 4]);
#pragma unroll
      for (int k = 0; k < 9; k++) {
        float4 bv = *reinterpret_cast<const float4*>(&Bs[(tc + 16 * k) * 68 + n4 * 4]);
#pragma unroll
        for (int i = 0; i < 4; i++) {
          acc[i][k] = fmaf(p[i].x, bv.x, acc[i][k]);
          acc[i][k] = fmaf(p[i].y, bv.y, acc[i][k]);
          acc[i][k] = fmaf(p[i].z, bv.z, acc[i][k]);
          acc[i][k] = fmaf(p[i].w, bv.w, acc[i][k]);
        }
      }
    }
    __syncthreads();
  }

  // deposit den columns
#pragma unroll
  for (int k = 0; k < 9; k++) {
    int col = tc + 16 * k;
    int b = col / 18, s = col - b * 18;
    if (s >= 16) {
#pragma unroll
      for (int i = 0; i < 4; i++)
        den_s[(b * 2 + (s - 16)) * 64 + tm + 16 * i] = acc[i][k];
    }
  }
  __syncthreads();
  // feat = num / den
#pragma unroll
  for (int k = 0; k < 9; k++) {
    int col = tc + 16 * k;
    int b = col / 18, s = col - b * 18;
    if (s < 16) {
      int e = s >> 3, c = s & 7;
#pragma unroll
      for (int i = 0; i < 4; i++) {
        int ml = tm + 16 * i;
        float d = den_s[(b * 2 + e) * 64 + ml];
        feat[((((size_t)b * 16 + l) * 2 + e) * 8 + c) * NSP + m0 + ml] = acc[i][k] / d;
      }
    }
  }
}

// ---------------- K3: final conv with group substitution + x_pi add ----------------
__global__ __launch_bounds__(256) void k3(
    const float* __restrict__ x, const float* __restrict__ w_pi, const float* __restrict__ w_conv,
    const float* __restrict__ shared_ws, const float* __restrict__ feat,
    float* __restrict__ out)
{
  __shared__ float wcs[8 * NC];
  __shared__ float wpis[64];
  __shared__ float sh[NC];
  __shared__ float cts[8];
  const int tid = threadIdx.x;
  const int j0 = blockIdx.x, b = blockIdx.y;
  for (int i = tid; i < 8 * NC; i += 256) wcs[i] = w_conv[j0 * 8 * NC + i];
  if (tid < 64) wpis[tid] = w_pi[j0 * 64 + tid];
  if (tid < NC) sh[tid] = shared_ws[b * NC + tid];
  __syncthreads();
  const int cnt = d_Gcnt[j0];
  if (tid < 8) {
    float v = 0.f;
    for (int c = 0; c < NC; c++) v = fmaf(wcs[tid * NC + c], sh[c], v);
    for (int g = 0; g < cnt; ++g) {
      int j1 = d_Gj1[j0][g];
      for (int cc = 0; cc < 8; ++cc) v -= wcs[tid * NC + j1 * 8 + cc] * sh[j1 * 8 + cc];
    }
    cts[tid] = v;
  }
  __syncthreads();
  const float* xb = x + (size_t)(b * NC + j0 * 8) * NSP;
  for (int it = 0; it < 7; ++it) {
    int n = it * 256 + tid;
    if (n < NSP) {
      float xv[8];
#pragma unroll
      for (int c = 0; c < 8; c++) xv[c] = xb[c * NSP + n];
      float o8[8];
#pragma unroll
      for (int o = 0; o < 8; o++) {
        float pi = 0.f;
#pragma unroll
        for (int c = 0; c < 8; c++) pi = fmaf(wpis[o * 8 + c], xv[c], pi);
        o8[o] = cts[o] + pi;
      }
      for (int g = 0; g < cnt; ++g) {
        int j1 = d_Gj1[j0][g], lim = d_Glim[j0][g], e = d_Ge[j0][g];
        float fv[8];
#pragma unroll
        for (int cc = 0; cc < 8; cc++)
          fv[cc] = feat[((((size_t)b * 16 + lim) * 2 + e) * 8 + cc) * NSP + n];
#pragma unroll
        for (int o = 0; o < 8; o++)
#pragma unroll
          for (int cc = 0; cc < 8; cc++)
            o8[o] = fmaf(wcs[o * NC + j1 * 8 + cc], fv[cc], o8[o]);
      }
#pragma unroll
      for (int o = 0; o < 8; o++)
        out[(size_t)(b * NC + j0 * 8 + o) * NSP + n] = o8[o];
    }
  }
}

extern "C" void kernel_launch(void* const* d_in, const int* in_sizes, int n_in,
                              void* d_out, int out_size, void* d_ws, size_t ws_size,
                              hipStream_t stream) {
  const float* x         = (const float*)d_in[0];
  const float* w_pi      = (const float*)d_in[1];
  const float* w_att     = (const float*)d_in[2];
  const float* w_conv    = (const float*)d_in[3];
  const float* limb_mean = (const float*)d_in[4];
  const float* limb_std  = (const float*)d_in[5];

  float* out   = (float*)d_out;
  float* A_out = out + 1880064;            // out(8*136*1728) then A(8*17*1728)

  float* ws         = (float*)d_ws;
  float* W_weighted = ws;                  // 1,880,064 floats
  float* W_A        = ws + WA_OFF;         //   235,008
  float* W_shared   = ws + 2115072;        //     1,088
  float* W_mmax     = ws + 2116160;        //    27,648
  float* W_feat     = ws + 2143808;        // 3,538,944  (total ~22.7 MB)

  hipLaunchKernelGGL(k1, dim3(NJ, NBATCH), dim3(256), 0, stream,
                     x, w_pi, w_att, A_out, W_A, W_weighted, W_shared);
  hipLaunchKernelGGL(k2a, dim3(6912), dim3(256), 0, stream,
                     limb_mean, limb_std, W_mmax);
  hipLaunchKernelGGL(k2b, dim3(27, 16), dim3(256), 0, stream,
                     limb_mean, limb_std, ws, W_mmax, W_feat);
  hipLaunchKernelGGL(k3, dim3(NJ, NBATCH), dim3(256), 0, stream,
                     x, w_pi, w_conv, W_shared, W_feat, out);
}

// Round 3
// 218.341 us; speedup vs baseline: 2.6377x; 2.6377x over previous
//
#include <hip/hip_runtime.h>
#include <math.h>

#define NJ 17
#define CPJ 8
#define NBATCH 8
#define NSP 1728
#define NC 136
#define WA_OFF 1880064  // element offset of bf16 A copy inside bf16 ws region
#define BST 72          // padded LDS stride (bf16 elements) = 144 B

typedef short short8 __attribute__((ext_vector_type(8)));
typedef float f32x4 __attribute__((ext_vector_type(4)));

__device__ __forceinline__ short f2bf(float f) {
  unsigned u = __builtin_bit_cast(unsigned, f);
  u += 0x7FFFu + ((u >> 16) & 1u);   // RNE
  return (short)(u >> 16);
}

__device__ const int d_CA[16] = {0,1,2,5,4,3,6,7,8,9,8,11,10,8,13,14};
__device__ const int d_CB[16] = {1,2,6,4,3,6,7,8,16,16,12,12,11,13,14,15};
__device__ const int d_Gcnt[17] = {1,2,2,2,2,1,3,2,4,1,1,2,2,2,2,1,2};
__device__ const int d_Gj1[17][4] = {
  {1,0,0,0},{0,2,0,0},{1,6,0,0},{4,6,0,0},{5,3,0,0},{4,0,0,0},{2,3,7,0},{6,8,0,0},
  {7,16,12,13},{16,0,0,0},{11,0,0,0},{12,10,0,0},{8,11,0,0},{8,14,0,0},{13,15,0,0},
  {14,0,0,0},{8,9,0,0}};
__device__ const int d_Glim[17][4] = {
  {0,0,0,0},{0,1,0,0},{1,2,0,0},{4,5,0,0},{3,4,0,0},{3,0,0,0},{2,5,6,0},{6,7,0,0},
  {7,8,10,13},{9,0,0,0},{12,0,0,0},{11,12,0,0},{10,11,0,0},{13,14,0,0},{14,15,0,0},
  {15,0,0,0},{8,9,0,0}};
__device__ const int d_Ge[17][4] = {
  {1,0,0,0},{0,1,0,0},{0,1,0,0},{0,1,0,0},{0,1,0,0},{1,0,0,0},{0,0,1,0},{0,1,0,0},
  {0,1,1,1},{1,0,0,0},{1,0,0,0},{1,0,0,0},{0,0,0,0},{0,1,0,0},{0,1,0,0},
  {0,0,0,0},{0,0,0,0}};

// ---------------- K1: per (b,j) attention softmax, weighted(bf16), shared ----------------
__global__ __launch_bounds__(256) void k1(
    const float* __restrict__ x, const float* __restrict__ w_pi, const float* __restrict__ w_att,
    float* __restrict__ A_out, short* __restrict__ A_bf,
    short* __restrict__ weighted_bf, float* __restrict__ shared_ws)
{
  __shared__ __attribute__((aligned(16))) float s_lds[NSP];
  __shared__ float wpis[64];
  __shared__ float redA[4], redB[4];
  __shared__ float shred[4][8];
  const int tid = threadIdx.x, lane = tid & 63, wid = tid >> 6;
  const int j = blockIdx.x, b = blockIdx.y;
  if (tid < 64) wpis[tid] = w_pi[j * 64 + tid];
  float wa[8];
#pragma unroll
  for (int c = 0; c < 8; c++) wa[c] = w_att[j * 8 + c];
  __syncthreads();
  const float* xb = x + (size_t)(b * NC + j * 8) * NSP;
  float lmax = -1e30f;
  for (int it = 0; it < 7; ++it) {
    int n = it * 256 + tid;
    if (n < NSP) {
      float s = 0.f;
#pragma unroll
      for (int c = 0; c < 8; c++) s = fmaf(wa[c], xb[c * NSP + n], s);
      s_lds[n] = s;
      lmax = fmaxf(lmax, s);
    }
  }
#pragma unroll
  for (int off = 32; off >= 1; off >>= 1) lmax = fmaxf(lmax, __shfl_xor(lmax, off));
  if (lane == 0) redA[wid] = lmax;
  __syncthreads();
  const float M = fmaxf(fmaxf(redA[0], redA[1]), fmaxf(redA[2], redA[3]));
  float lsum = 0.f;
  for (int it = 0; it < 7; ++it) {
    int n = it * 256 + tid;
    if (n < NSP) { float e = __expf(s_lds[n] - M); s_lds[n] = e; lsum += e; }
  }
#pragma unroll
  for (int off = 32; off >= 1; off >>= 1) lsum += __shfl_xor(lsum, off);
  if (lane == 0) redB[wid] = lsum;
  __syncthreads();
  const float inv = 1.0f / (redB[0] + redB[1] + redB[2] + redB[3]);
  float sh[8];
#pragma unroll
  for (int o = 0; o < 8; o++) sh[o] = 0.f;
  const int aoff = (b * NJ + j) * NSP;
  for (int it = 0; it < 7; ++it) {
    int n = it * 256 + tid;
    if (n < NSP) {
      float a = s_lds[n] * inv;
      A_out[aoff + n] = a;
      A_bf[aoff + n] = f2bf(a);
      float xv[8];
#pragma unroll
      for (int c = 0; c < 8; c++) xv[c] = xb[c * NSP + n];
#pragma unroll
      for (int o = 0; o < 8; o++) {
        float pi = 0.f;
#pragma unroll
        for (int c = 0; c < 8; c++) pi = fmaf(wpis[o * 8 + c], xv[c], pi);
        float w = pi * a;
        weighted_bf[(size_t)((b * NJ + j) * 8 + o) * NSP + n] = f2bf(w);
        sh[o] += w;
      }
    }
  }
#pragma unroll
  for (int o = 0; o < 8; o++) {
    float v = sh[o];
#pragma unroll
    for (int off = 32; off >= 1; off >>= 1) v += __shfl_xor(v, off);
    if (lane == 0) shred[wid][o] = v;
  }
  __syncthreads();
  if (tid < 8)
    shared_ws[b * NC + j * 8 + tid] = shred[0][tid] + shred[1][tid] + shred[2][tid] + shred[3][tid];
}

// ---------------- K2b: fused P-gen + bf16 MFMA GEMM + den-divide -> feat ----------------
__global__ __launch_bounds__(256) void k2b(
    const float* __restrict__ limb_mean, const float* __restrict__ limb_std,
    const short* __restrict__ wbf, float* __restrict__ feat)
{
  const float SPf = 2500.0f / 11.0f;
  const float LOG2E = 1.4426950408889634f;
  __shared__ __attribute__((aligned(16))) short Bs[144 * BST];  // 20736 B
  __shared__ __attribute__((aligned(16))) short Ps[64 * BST];   //  9216 B
  __shared__ float den_s[16 * 64];                              //  4096 B
  __shared__ int rowbase[144];
  __shared__ float mposx[64], mposy[64], mposz[64];

  const int tid = threadIdx.x;
  const int l = blockIdx.y;
  const int m0 = blockIdx.x * 64;

  if (tid < 144) {
    int b = tid / 18, s = tid - b * 18;
    int ja = d_CA[l], jb = d_CB[l];
    int off;
    if (s < 8)        off = ((b * NJ + ja) * CPJ + s) * NSP;
    else if (s < 16)  off = ((b * NJ + jb) * CPJ + (s - 8)) * NSP;
    else if (s == 16) off = WA_OFF + (b * NJ + ja) * NSP;
    else              off = WA_OFF + (b * NJ + jb) * NSP;
    rowbase[tid] = off;
  }
  if (tid < 64) {
    int m = m0 + tid;
    int imx = m / 144, rem = m - imx * 144, imy = rem / 12, imz = rem - imy * 12;
    mposx[tid] = (float)imx; mposy[tid] = (float)imy; mposz[tid] = (float)imz;
  }
  const float mean = limb_mean[l];
  const float sd = limb_std[l];
  const float invd2 = LOG2E / (20.0f * sd * sd + 0.1f);  // folded log2(e)

  f32x4 acc[9];
#pragma unroll
  for (int c = 0; c < 9; c++) acc[c] = (f32x4){0.f, 0.f, 0.f, 0.f};

  const int nn = tid & 63;
  const int mb = tid >> 6;
  const int lane = tid & 63, wid = tid >> 6;
  const int lrow = lane & 15;
  const int lk = (lane >> 4) * 8;

  __syncthreads();

  for (int nt = 0; nt < 27; ++nt) {
    const int n0 = nt * 64;
    // ---- stage B tile: 144 rows x 64 n, bf16, 16B chunks ----
#pragma unroll
    for (int it = 0; it < 5; ++it) {
      int c = tid + 256 * it;
      if (c < 1152) {
        int row = c >> 3, o8 = (c & 7) * 8;
        const int4 v = *reinterpret_cast<const int4*>(wbf + rowbase[row] + n0 + o8);
        *reinterpret_cast<int4*>(&Bs[row * BST + o8]) = v;
      }
    }
    // ---- generate P tile: 64 m x 64 n ----
    {
      int n = n0 + nn;
      int inx = n / 144, nrem = n - inx * 144, iny = nrem / 12, inz = nrem - iny * 12;
      float fnx = (float)inx, fny = (float)iny, fnz = (float)inz;
#pragma unroll
      for (int mi = 0; mi < 16; ++mi) {
        int ml = mb + 4 * mi;
        float dx = mposx[ml] - fnx, dy = mposy[ml] - fny, dz = mposz[ml] - fnz;
        float d2 = fmaf(dx, dx, fmaf(dy, dy, dz * dz));
        float t = fmaf(SPf, sqrtf(d2), -mean);
        float arg = -(t * invd2) * t;           // log2-domain
        Ps[ml * BST + nn] = f2bf(exp2f(arg));
      }
    }
    __syncthreads();
    // ---- MFMA phase: wave wid owns m-strip [wid*16, wid*16+16) x all 144 cols ----
    const short* pbase = &Ps[(wid * 16 + lrow) * BST + lk];
#pragma unroll
    for (int kk = 0; kk < 64; kk += 32) {
      short8 a = *reinterpret_cast<const short8*>(pbase + kk);
#pragma unroll
      for (int c = 0; c < 9; ++c) {
        short8 bfrag = *reinterpret_cast<const short8*>(&Bs[(c * 16 + lrow) * BST + kk + lk]);
        acc[c] = __builtin_amdgcn_mfma_f32_16x16x32_bf16(a, bfrag, acc[c], 0, 0, 0);
      }
    }
    __syncthreads();
  }

  // ---- epilogue: deposit reciprocal den, then feat = num * (1/den) ----
  const int mloc = wid * 16 + 4 * (lane >> 4);  // + r
#pragma unroll
  for (int c = 0; c < 9; ++c) {
    int col = c * 16 + lrow;
    int b = col / 18, s = col - b * 18;
    if (s >= 16) {
#pragma unroll
      for (int r = 0; r < 4; ++r)
        den_s[(b * 2 + (s - 16)) * 64 + mloc + r] = 1.0f / acc[c][r];
    }
  }
  __syncthreads();
#pragma unroll
  for (int c = 0; c < 9; ++c) {
    int col = c * 16 + lrow;
    int b = col / 18, s = col - b * 18;
    if (s < 16) {
      int e = s >> 3, ch = s & 7;
#pragma unroll
      for (int r = 0; r < 4; ++r) {
        float rd = den_s[(b * 2 + e) * 64 + mloc + r];
        feat[((((size_t)b * 16 + l) * 2 + e) * 8 + ch) * NSP + m0 + mloc + r] = acc[c][r] * rd;
      }
    }
  }
}

// ---------------- K3: final conv with group substitution + x_pi add ----------------
__global__ __launch_bounds__(256) void k3(
    const float* __restrict__ x, const float* __restrict__ w_pi, const float* __restrict__ w_conv,
    const float* __restrict__ shared_ws, const float* __restrict__ feat,
    float* __restrict__ out)
{
  __shared__ float wcs[8 * NC];
  __shared__ float wpis[64];
  __shared__ float sh[NC];
  __shared__ float cts[8];
  const int tid = threadIdx.x;
  const int j0 = blockIdx.x, b = blockIdx.y;
  for (int i = tid; i < 8 * NC; i += 256) wcs[i] = w_conv[j0 * 8 * NC + i];
  if (tid < 64) wpis[tid] = w_pi[j0 * 64 + tid];
  if (tid < NC) sh[tid] = shared_ws[b * NC + tid];
  __syncthreads();
  const int cnt = d_Gcnt[j0];
  if (tid < 8) {
    float v = 0.f;
    for (int c = 0; c < NC; c++) v = fmaf(wcs[tid * NC + c], sh[c], v);
    for (int g = 0; g < cnt; ++g) {
      int j1 = d_Gj1[j0][g];
      for (int cc = 0; cc < 8; ++cc) v -= wcs[tid * NC + j1 * 8 + cc] * sh[j1 * 8 + cc];
    }
    cts[tid] = v;
  }
  __syncthreads();
  const float* xb = x + (size_t)(b * NC + j0 * 8) * NSP;
  for (int it = 0; it < 7; ++it) {
    int n = it * 256 + tid;
    if (n < NSP) {
      float xv[8];
#pragma unroll
      for (int c = 0; c < 8; c++) xv[c] = xb[c * NSP + n];
      float o8[8];
#pragma unroll
      for (int o = 0; o < 8; o++) {
        float pi = 0.f;
#pragma unroll
        for (int c = 0; c < 8; c++) pi = fmaf(wpis[o * 8 + c], xv[c], pi);
        o8[o] = cts[o] + pi;
      }
      for (int g = 0; g < cnt; ++g) {
        int j1 = d_Gj1[j0][g], lim = d_Glim[j0][g], e = d_Ge[j0][g];
        float fv[8];
#pragma unroll
        for (int cc = 0; cc < 8; cc++)
          fv[cc] = feat[((((size_t)b * 16 + lim) * 2 + e) * 8 + cc) * NSP + n];
#pragma unroll
        for (int o = 0; o < 8; o++)
#pragma unroll
          for (int cc = 0; cc < 8; cc++)
            o8[o] = fmaf(wcs[o * NC + j1 * 8 + cc], fv[cc], o8[o]);
      }
#pragma unroll
      for (int o = 0; o < 8; o++)
        out[(size_t)(b * NC + j0 * 8 + o) * NSP + n] = o8[o];
    }
  }
}

extern "C" void kernel_launch(void* const* d_in, const int* in_sizes, int n_in,
                              void* d_out, int out_size, void* d_ws, size_t ws_size,
                              hipStream_t stream) {
  const float* x         = (const float*)d_in[0];
  const float* w_pi      = (const float*)d_in[1];
  const float* w_att     = (const float*)d_in[2];
  const float* w_conv    = (const float*)d_in[3];
  const float* limb_mean = (const float*)d_in[4];
  const float* limb_std  = (const float*)d_in[5];

  float* out   = (float*)d_out;
  float* A_out = out + 1880064;            // out(8*136*1728) then A(8*17*1728)

  short* W_bf     = (short*)d_ws;                          // weighted(1,880,064) + A(235,008) bf16
  float* W_shared = (float*)((char*)d_ws + 4230144);       // 1,088 floats
  float* W_feat   = (float*)((char*)d_ws + 4234496);       // 3,538,944 floats

  hipLaunchKernelGGL(k1, dim3(NJ, NBATCH), dim3(256), 0, stream,
                     x, w_pi, w_att, A_out, W_bf + WA_OFF, W_bf, W_shared);
  hipLaunchKernelGGL(k2b, dim3(27, 16), dim3(256), 0, stream,
                     limb_mean, limb_std, W_bf, W_feat);
  hipLaunchKernelGGL(k3, dim3(NJ, NBATCH), dim3(256), 0, stream,
                     x, w_pi, w_conv, W_shared, W_feat, out);
}

// Round 4
// 166.686 us; speedup vs baseline: 3.4551x; 1.3099x over previous
//
#include <hip/hip_runtime.h>
#include <math.h>

#define NJ 17
#define CPJ 8
#define NBATCH 8
#define NSP 1728
#define NC 136
#define WA_OFF 1880064  // element offset of bf16 A copy inside bf16 ws region
#define BQ 80           // Bs LDS stride (bf16 elems)
#define PQ 72           // Ps LDS stride (bf16 elems)

typedef short short8 __attribute__((ext_vector_type(8)));
typedef float f32x4 __attribute__((ext_vector_type(4)));

__device__ __forceinline__ short f2bf(float f) {
  unsigned u = __builtin_bit_cast(unsigned, f);
  u += 0x7FFFu + ((u >> 16) & 1u);   // RNE
  return (short)(u >> 16);
}

__device__ const int d_CA[16] = {0,1,2,5,4,3,6,7,8,9,8,11,10,8,13,14};
__device__ const int d_CB[16] = {1,2,6,4,3,6,7,8,16,16,12,12,11,13,14,15};
__device__ const int d_Gcnt[17] = {1,2,2,2,2,1,3,2,4,1,1,2,2,2,2,1,2};
__device__ const int d_Gj1[17][4] = {
  {1,0,0,0},{0,2,0,0},{1,6,0,0},{4,6,0,0},{5,3,0,0},{4,0,0,0},{2,3,7,0},{6,8,0,0},
  {7,16,12,13},{16,0,0,0},{11,0,0,0},{12,10,0,0},{8,11,0,0},{8,14,0,0},{13,15,0,0},
  {14,0,0,0},{8,9,0,0}};
__device__ const int d_Glim[17][4] = {
  {0,0,0,0},{0,1,0,0},{1,2,0,0},{4,5,0,0},{3,4,0,0},{3,0,0,0},{2,5,6,0},{6,7,0,0},
  {7,8,10,13},{9,0,0,0},{12,0,0,0},{11,12,0,0},{10,11,0,0},{13,14,0,0},{14,15,0,0},
  {15,0,0,0},{8,9,0,0}};
__device__ const int d_Ge[17][4] = {
  {1,0,0,0},{0,1,0,0},{0,1,0,0},{0,1,0,0},{0,1,0,0},{1,0,0,0},{0,0,1,0},{0,1,0,0},
  {0,1,1,1},{1,0,0,0},{1,0,0,0},{1,0,0,0},{0,0,0,0},{0,1,0,0},{0,1,0,0},
  {0,0,0,0},{0,0,0,0}};

// ---------------- K1a: per (b,j,chunk) partial softmax stats ----------------
__global__ __launch_bounds__(256) void k1a(
    const float* __restrict__ x, const float* __restrict__ w_att,
    float* __restrict__ pmax, float* __restrict__ psum)
{
  __shared__ float red[8];
  const int tid = threadIdx.x, lane = tid & 63, wid = tid >> 6;
  const int j = blockIdx.x, b = blockIdx.y, ck = blockIdx.z;
  const int nb = ck * 432;
  float wa[8];
#pragma unroll
  for (int c = 0; c < 8; c++) wa[c] = w_att[j * 8 + c];
  const float* xb = x + (size_t)(b * NC + j * 8) * NSP;
  const int n0 = nb + tid, n1 = nb + tid + 256;
  const bool v1 = tid < 176;
  float s0 = 0.f, s1 = 0.f;
#pragma unroll
  for (int c = 0; c < 8; c++) s0 = fmaf(wa[c], xb[c * NSP + n0], s0);
  if (v1) {
#pragma unroll
    for (int c = 0; c < 8; c++) s1 = fmaf(wa[c], xb[c * NSP + n1], s1);
  }
  float lmax = fmaxf(s0, v1 ? s1 : -3.4e38f);
#pragma unroll
  for (int off = 32; off >= 1; off >>= 1) lmax = fmaxf(lmax, __shfl_xor(lmax, off));
  if (lane == 0) red[wid] = lmax;
  __syncthreads();
  const float M = fmaxf(fmaxf(red[0], red[1]), fmaxf(red[2], red[3]));
  float lsum = __expf(s0 - M) + (v1 ? __expf(s1 - M) : 0.f);
#pragma unroll
  for (int off = 32; off >= 1; off >>= 1) lsum += __shfl_xor(lsum, off);
  if (lane == 0) red[4 + wid] = lsum;
  __syncthreads();
  if (tid == 0) {
    int r4 = (b * NJ + j) * 4 + ck;
    pmax[r4] = M;
    psum[r4] = red[4] + red[5] + red[6] + red[7];
  }
}

// ---------------- K1c: normalize, weighted(bf16), shared partials ----------------
__global__ __launch_bounds__(256) void k1c(
    const float* __restrict__ x, const float* __restrict__ w_pi, const float* __restrict__ w_att,
    const float* __restrict__ pmax, const float* __restrict__ psum,
    float* __restrict__ A_out, short* __restrict__ A_bf,
    short* __restrict__ weighted_bf, float* __restrict__ shpart)
{
  __shared__ float wpis[64];
  __shared__ float shred[4][8];
  const int tid = threadIdx.x, lane = tid & 63, wid = tid >> 6;
  const int j = blockIdx.x, b = blockIdx.y, ck = blockIdx.z;
  const int nb = ck * 432;
  if (tid < 64) wpis[tid] = w_pi[j * 64 + tid];
  float wa[8];
#pragma unroll
  for (int c = 0; c < 8; c++) wa[c] = w_att[j * 8 + c];
  const int r4 = (b * NJ + j) * 4;
  float pm0 = pmax[r4], pm1 = pmax[r4+1], pm2 = pmax[r4+2], pm3 = pmax[r4+3];
  float M = fmaxf(fmaxf(pm0, pm1), fmaxf(pm2, pm3));
  float S = psum[r4] * __expf(pm0 - M) + psum[r4+1] * __expf(pm1 - M)
          + psum[r4+2] * __expf(pm2 - M) + psum[r4+3] * __expf(pm3 - M);
  const float inv = 1.0f / S;
  __syncthreads();
  const float* xb = x + (size_t)(b * NC + j * 8) * NSP;
  const int aoff = (b * NJ + j) * NSP;
  float sh[8];
#pragma unroll
  for (int o = 0; o < 8; o++) sh[o] = 0.f;
#pragma unroll
  for (int i = 0; i < 2; ++i) {
    int n = nb + tid + 256 * i;
    if (i == 0 || tid < 176) {
      float s = 0.f;
      float xv[8];
#pragma unroll
      for (int c = 0; c < 8; c++) xv[c] = xb[c * NSP + n];
#pragma unroll
      for (int c = 0; c < 8; c++) s = fmaf(wa[c], xv[c], s);
      float a = __expf(s - M) * inv;
      A_out[aoff + n] = a;
      A_bf[aoff + n] = f2bf(a);
#pragma unroll
      for (int o = 0; o < 8; o++) {
        float pi = 0.f;
#pragma unroll
        for (int c = 0; c < 8; c++) pi = fmaf(wpis[o * 8 + c], xv[c], pi);
        float w = pi * a;
        weighted_bf[(size_t)((b * NJ + j) * 8 + o) * NSP + n] = f2bf(w);
        sh[o] += w;
      }
    }
  }
#pragma unroll
  for (int o = 0; o < 8; o++) {
    float v = sh[o];
#pragma unroll
    for (int off = 32; off >= 1; off >>= 1) v += __shfl_xor(v, off);
    if (lane == 0) shred[wid][o] = v;
  }
  __syncthreads();
  if (tid < 8)
    shpart[((b * NJ + j) * 8 + tid) * 4 + ck] =
        shred[0][tid] + shred[1][tid] + shred[2][tid] + shred[3][tid];
}

// ---------------- K2b: dbuf-staged, LUT P-gen, K-split bf16 MFMA GEMM ----------------
__global__ __launch_bounds__(256) void k2b(
    const float* __restrict__ limb_mean, const float* __restrict__ limb_std,
    const short* __restrict__ wbf, float* __restrict__ feat)
{
  const float SPf = 2500.0f / 11.0f;
  const float LOG2E = 1.4426950408889634f;
  __shared__ __attribute__((aligned(16))) short Bs[2][144 * BQ];  // 46080 B (also f32 scratch)
  __shared__ __attribute__((aligned(16))) short Ps[2][64 * PQ];   // 18432 B
  __shared__ float den_s[16 * 64];                                //  4096 B
  __shared__ short lut[364];
  __shared__ int rowbase[144];
  __shared__ int mpix[64], mpiy[64], mpiz[64];

  const int tid = threadIdx.x;
  const int l = blockIdx.y;
  const int m0 = blockIdx.x * 64;
  const int lane = tid & 63, wid = tid >> 6;
  const int lrow = lane & 15;
  const int lk8 = (lane >> 4) * 8;
  const int wrow = (wid & 1) * 32;      // rows owned by this wave
  const int kkb = (wid >> 1) * 32;      // K-split half

  const float mean = limb_mean[l];
  const float sd = limb_std[l];
  const float invd2 = LOG2E / (20.0f * sd * sd + 0.1f);

  // setup: lut, rowbase, m coords
  for (int i = tid; i < 364; i += 256) {
    float t = fmaf(SPf, sqrtf((float)i), -mean);
    lut[i] = f2bf(exp2f(-(t * invd2) * t));
  }
  if (tid < 144) {
    int b = tid / 18, s = tid - b * 18;
    int ja = d_CA[l], jb = d_CB[l];
    int off;
    if (s < 8)        off = ((b * NJ + ja) * CPJ + s) * NSP;
    else if (s < 16)  off = ((b * NJ + jb) * CPJ + (s - 8)) * NSP;
    else if (s == 16) off = WA_OFF + (b * NJ + ja) * NSP;
    else              off = WA_OFF + (b * NJ + jb) * NSP;
    rowbase[tid] = off;
  }
  if (tid < 64) {
    int m = m0 + tid;
    int imx = m / 144, rem = m - imx * 144, imy = rem / 12, imz = rem - imy * 12;
    mpix[tid] = imx; mpiy[tid] = imy; mpiz[tid] = imz;
  }
  __syncthreads();

  // per-thread staging addresses (constant across iters except n0)
  const short* gp[5];
  int ldsoff[5];
#pragma unroll
  for (int it = 0; it < 5; ++it) {
    int c = tid + 256 * it;
    int row = c >> 3, o8 = (c & 7) * 8;
    if (c < 1152) { gp[it] = wbf + rowbase[row] + o8; ldsoff[it] = row * BQ + o8; }
    else          { gp[it] = wbf; ldsoff[it] = 0; }
  }
  const bool g4 = tid < 128;
  const int nn = tid & 63;
  const int mb = wid;

  f32x4 acc0[9], acc1[9];
#pragma unroll
  for (int c = 0; c < 9; c++) { acc0[c] = (f32x4){0,0,0,0}; acc1[c] = (f32x4){0,0,0,0}; }

  // ---- prologue: stage tile 0 into buffer 0 ----
  {
    int4 v[5];
#pragma unroll
    for (int it = 0; it < 4; ++it) v[it] = *reinterpret_cast<const int4*>(gp[it]);
    if (g4) v[4] = *reinterpret_cast<const int4*>(gp[4]);
    // P-gen tile 0
    int n = nn;
    int inx = n / 144, nrem = n - inx * 144, iny = nrem / 12, inz = nrem - iny * 12;
#pragma unroll
    for (int mi = 0; mi < 16; ++mi) {
      int ml = mb + 4 * mi;
      int dx = mpix[ml] - inx, dy = mpiy[ml] - iny, dz = mpiz[ml] - inz;
      int d2 = dx * dx + dy * dy + dz * dz;
      Ps[0][ml * PQ + nn] = lut[d2];
    }
#pragma unroll
    for (int it = 0; it < 4; ++it) *reinterpret_cast<int4*>(&Bs[0][ldsoff[it]]) = v[it];
    if (g4) *reinterpret_cast<int4*>(&Bs[0][ldsoff[4]]) = v[4];
  }
  __syncthreads();

  int cur = 0;
  for (int nt = 0; nt < 27; ++nt) {
    int4 v[5];
    const int n0n = (nt + 1) * 64;
    if (nt < 26) {
#pragma unroll
      for (int it = 0; it < 4; ++it) v[it] = *reinterpret_cast<const int4*>(gp[it] + n0n);
      if (g4) v[4] = *reinterpret_cast<const int4*>(gp[4] + n0n);
    }
    // ---- MFMA on [cur]: this wave's rows at its K-half ----
    {
      const short* pA = &Ps[cur][(wrow + lrow) * PQ + kkb + lk8];
      short8 a0 = *reinterpret_cast<const short8*>(pA);
      short8 a1 = *reinterpret_cast<const short8*>(pA + 16 * PQ);
#pragma unroll
      for (int c = 0; c < 9; ++c) {
        short8 bf = *reinterpret_cast<const short8*>(&Bs[cur][(c * 16 + lrow) * BQ + kkb + lk8]);
        acc0[c] = __builtin_amdgcn_mfma_f32_16x16x32_bf16(a0, bf, acc0[c], 0, 0, 0);
        acc1[c] = __builtin_amdgcn_mfma_f32_16x16x32_bf16(a1, bf, acc1[c], 0, 0, 0);
      }
    }
    if (nt < 26) {
      const int dst = cur ^ 1;
      // P-gen tile nt+1
      int n = n0n + nn;
      int inx = n / 144, nrem = n - inx * 144, iny = nrem / 12, inz = nrem - iny * 12;
#pragma unroll
      for (int mi = 0; mi < 16; ++mi) {
        int ml = mb + 4 * mi;
        int dx = mpix[ml] - inx, dy = mpiy[ml] - iny, dz = mpiz[ml] - inz;
        int d2 = dx * dx + dy * dy + dz * dz;
        Ps[dst][ml * PQ + nn] = lut[d2];
      }
#pragma unroll
      for (int it = 0; it < 4; ++it) *reinterpret_cast<int4*>(&Bs[dst][ldsoff[it]]) = v[it];
      if (g4) *reinterpret_cast<int4*>(&Bs[dst][ldsoff[4]]) = v[4];
    }
    __syncthreads();
    cur ^= 1;
  }

  // ---- epilogue: K-split reduce (waves 2,3 -> scratch; waves 0,1 add) ----
  float* scratch = reinterpret_cast<float*>(&Bs[0][0]);  // 64*144*4 = 36864 B
  const int rbase = 4 * (lane >> 4);
  if (wid >= 2) {
#pragma unroll
    for (int c = 0; c < 9; ++c) {
#pragma unroll
      for (int r = 0; r < 4; ++r) {
        scratch[(wrow + rbase + r) * 144 + c * 16 + lrow] = acc0[c][r];
        scratch[(wrow + 16 + rbase + r) * 144 + c * 16 + lrow] = acc1[c][r];
      }
    }
  }
  __syncthreads();
  if (wid < 2) {
#pragma unroll
    for (int c = 0; c < 9; ++c) {
#pragma unroll
      for (int r = 0; r < 4; ++r) {
        acc0[c][r] += scratch[(wrow + rbase + r) * 144 + c * 16 + lrow];
        acc1[c][r] += scratch[(wrow + 16 + rbase + r) * 144 + c * 16 + lrow];
      }
    }
    // deposit reciprocal den
#pragma unroll
    for (int c = 0; c < 9; ++c) {
      int col = c * 16 + lrow;
      int b = col / 18, s = col - b * 18;
      if (s >= 16) {
#pragma unroll
        for (int r = 0; r < 4; ++r) {
          den_s[(b * 2 + (s - 16)) * 64 + wrow + rbase + r] = 1.0f / acc0[c][r];
          den_s[(b * 2 + (s - 16)) * 64 + wrow + 16 + rbase + r] = 1.0f / acc1[c][r];
        }
      }
    }
  }
  __syncthreads();
  if (wid < 2) {
#pragma unroll
    for (int c = 0; c < 9; ++c) {
      int col = c * 16 + lrow;
      int b = col / 18, s = col - b * 18;
      if (s < 16) {
        int e = s >> 3, ch = s & 7;
        size_t obase = ((size_t)(b * 16 + l) * 2 + e) * (NSP * 8) + ch;
#pragma unroll
        for (int r = 0; r < 4; ++r) {
          int m1 = wrow + rbase + r, m2 = wrow + 16 + rbase + r;
          feat[obase + (size_t)(m0 + m1) * 8] = acc0[c][r] * den_s[(b * 2 + e) * 64 + m1];
          feat[obase + (size_t)(m0 + m2) * 8] = acc1[c][r] * den_s[(b * 2 + e) * 64 + m2];
        }
      }
    }
  }
}

// ---------------- K3: final conv with group substitution + x_pi add ----------------
__global__ __launch_bounds__(256) void k3(
    const float* __restrict__ x, const float* __restrict__ w_pi, const float* __restrict__ w_conv,
    const float* __restrict__ shpart, const float* __restrict__ feat,
    float* __restrict__ out)
{
  __shared__ float wcs[8 * NC];
  __shared__ float wpis[64];
  __shared__ float sh[NC];
  __shared__ float cts[8];
  const int tid = threadIdx.x;
  const int j0 = blockIdx.x, b = blockIdx.y;
  const int n = blockIdx.z * 256 + tid;
  for (int i = tid; i < 8 * NC; i += 256) wcs[i] = w_conv[j0 * 8 * NC + i];
  if (tid < 64) wpis[tid] = w_pi[j0 * 64 + tid];
  if (tid < NC) {
    const float* p = shpart + ((b * NJ) * 8 + tid) * 4;  // channel tid of batch b
    sh[tid] = p[0] + p[1] + p[2] + p[3];
  }
  __syncthreads();
  const int cnt = d_Gcnt[j0];
  if (tid < 8) {
    float v = 0.f;
    for (int c = 0; c < NC; c++) v = fmaf(wcs[tid * NC + c], sh[c], v);
    for (int g = 0; g < cnt; ++g) {
      int j1 = d_Gj1[j0][g];
      for (int cc = 0; cc < 8; ++cc) v -= wcs[tid * NC + j1 * 8 + cc] * sh[j1 * 8 + cc];
    }
    cts[tid] = v;
  }
  __syncthreads();
  if (n < NSP) {
    const float* xb = x + (size_t)(b * NC + j0 * 8) * NSP;
    float xv[8];
#pragma unroll
    for (int c = 0; c < 8; c++) xv[c] = xb[c * NSP + n];
    float o8[8];
#pragma unroll
    for (int o = 0; o < 8; o++) {
      float pi = 0.f;
#pragma unroll
      for (int c = 0; c < 8; c++) pi = fmaf(wpis[o * 8 + c], xv[c], pi);
      o8[o] = cts[o] + pi;
    }
    for (int g = 0; g < cnt; ++g) {
      int j1 = d_Gj1[j0][g], lim = d_Glim[j0][g], e = d_Ge[j0][g];
      const float* fb = feat + ((size_t)(b * 16 + lim) * 2 + e) * (NSP * 8) + (size_t)n * 8;
      float4 flo = *reinterpret_cast<const float4*>(fb);
      float4 fhi = *reinterpret_cast<const float4*>(fb + 4);
      float fv[8] = {flo.x, flo.y, flo.z, flo.w, fhi.x, fhi.y, fhi.z, fhi.w};
#pragma unroll
      for (int o = 0; o < 8; o++)
#pragma unroll
        for (int cc = 0; cc < 8; cc++)
          o8[o] = fmaf(wcs[o * NC + j1 * 8 + cc], fv[cc], o8[o]);
    }
#pragma unroll
    for (int o = 0; o < 8; o++)
      out[(size_t)(b * NC + j0 * 8 + o) * NSP + n] = o8[o];
  }
}

extern "C" void kernel_launch(void* const* d_in, const int* in_sizes, int n_in,
                              void* d_out, int out_size, void* d_ws, size_t ws_size,
                              hipStream_t stream) {
  const float* x         = (const float*)d_in[0];
  const float* w_pi      = (const float*)d_in[1];
  const float* w_att     = (const float*)d_in[2];
  const float* w_conv    = (const float*)d_in[3];
  const float* limb_mean = (const float*)d_in[4];
  const float* limb_std  = (const float*)d_in[5];

  float* out   = (float*)d_out;
  float* A_out = out + 1880064;            // out(8*136*1728) then A(8*17*1728)

  short* W_bf    = (short*)d_ws;                          // weighted(1,880,064) + A(235,008) bf16
  char*  base    = (char*)d_ws + 4230144;
  float* W_pmax  = (float*)base;                          // 544
  float* W_psum  = (float*)(base + 2176);                 // 544
  float* W_shp   = (float*)(base + 4352);                 // 4352
  float* W_feat  = (float*)(base + 21760);                // 3,538,944 floats [b][l][e][n][ch]

  hipLaunchKernelGGL(k1a, dim3(NJ, NBATCH, 4), dim3(256), 0, stream,
                     x, w_att, W_pmax, W_psum);
  hipLaunchKernelGGL(k1c, dim3(NJ, NBATCH, 4), dim3(256), 0, stream,
                     x, w_pi, w_att, W_pmax, W_psum, A_out, W_bf + WA_OFF, W_bf, W_shp);
  hipLaunchKernelGGL(k2b, dim3(27, 16), dim3(256), 0, stream,
                     limb_mean, limb_std, W_bf, W_feat);
  hipLaunchKernelGGL(k3, dim3(NJ, NBATCH, 7), dim3(256), 0, stream,
                     x, w_pi, w_conv, W_shp, W_feat, out);
}

// Round 6
// 157.101 us; speedup vs baseline: 3.6659x; 1.0610x over previous
//
#include <hip/hip_runtime.h>
#include <math.h>

#define NJ 17
#define CPJ 8
#define NBATCH 8
#define NSP 1728
#define NC 136
#define WA_OFF 1880064  // element offset of bf16 A copy inside bf16 ws region
#define SST 148         // epilogue scratch stride (floats)

typedef short short8 __attribute__((ext_vector_type(8)));
typedef float f32x4 __attribute__((ext_vector_type(4)));

__device__ __forceinline__ short f2bf(float f) {
  unsigned u = __builtin_bit_cast(unsigned, f);
  u += 0x7FFFu + ((u >> 16) & 1u);   // RNE
  return (short)(u >> 16);
}

__device__ const int d_CA[16] = {0,1,2,5,4,3,6,7,8,9,8,11,10,8,13,14};
__device__ const int d_CB[16] = {1,2,6,4,3,6,7,8,16,16,12,12,11,13,14,15};
__device__ const int d_Gcnt[17] = {1,2,2,2,2,1,3,2,4,1,1,2,2,2,2,1,2};
__device__ const int d_Gj1[17][4] = {
  {1,0,0,0},{0,2,0,0},{1,6,0,0},{4,6,0,0},{5,3,0,0},{4,0,0,0},{2,3,7,0},{6,8,0,0},
  {7,16,12,13},{16,0,0,0},{11,0,0,0},{12,10,0,0},{8,11,0,0},{8,14,0,0},{13,15,0,0},
  {14,0,0,0},{8,9,0,0}};
__device__ const int d_Glim[17][4] = {
  {0,0,0,0},{0,1,0,0},{1,2,0,0},{4,5,0,0},{3,4,0,0},{3,0,0,0},{2,5,6,0},{6,7,0,0},
  {7,8,10,13},{9,0,0,0},{12,0,0,0},{11,12,0,0},{10,11,0,0},{13,14,0,0},{14,15,0,0},
  {15,0,0,0},{8,9,0,0}};
__device__ const int d_Ge[17][4] = {
  {1,0,0,0},{0,1,0,0},{0,1,0,0},{0,1,0,0},{0,1,0,0},{1,0,0,0},{0,0,1,0},{0,1,0,0},
  {0,1,1,1},{1,0,0,0},{1,0,0,0},{1,0,0,0},{0,0,0,0},{0,1,0,0},{0,1,0,0},
  {0,0,0,0},{0,0,0,0}};

// ---------------- K1: fused per (b,j) softmax + weighted(bf16) + shared ----------------
__global__ __launch_bounds__(256) void k1(
    const float* __restrict__ x, const float* __restrict__ w_pi, const float* __restrict__ w_att,
    float* __restrict__ A_out, short* __restrict__ A_bf,
    short* __restrict__ weighted_bf, float* __restrict__ shared_ws)
{
  __shared__ __attribute__((aligned(16))) float xs[8 * NSP];   // 55296 B
  __shared__ float slg[NSP];                                    //  6912 B
  __shared__ float wpis[64];
  __shared__ float red[8];
  __shared__ float shred[4][8];
  const int tid = threadIdx.x, lane = tid & 63, wid = tid >> 6;
  const int j = blockIdx.x, b = blockIdx.y;
  const float* xb = x + (size_t)(b * NC + j * 8) * NSP;
  // stage the whole contiguous 8x1728 slice
  for (int i = tid; i < (8 * NSP) / 4; i += 256)
    reinterpret_cast<float4*>(xs)[i] = reinterpret_cast<const float4*>(xb)[i];
  if (tid < 64) wpis[tid] = w_pi[j * 64 + tid];
  float wa[8];
#pragma unroll
  for (int c = 0; c < 8; c++) wa[c] = w_att[j * 8 + c];
  __syncthreads();
  float lmax = -3.4e38f;
  for (int it = 0; it < 7; ++it) {
    int n = it * 256 + tid;
    if (n < NSP) {
      float s = 0.f;
#pragma unroll
      for (int c = 0; c < 8; c++) s = fmaf(wa[c], xs[c * NSP + n], s);
      slg[n] = s;
      lmax = fmaxf(lmax, s);
    }
  }
#pragma unroll
  for (int off = 32; off >= 1; off >>= 1) lmax = fmaxf(lmax, __shfl_xor(lmax, off));
  if (lane == 0) red[wid] = lmax;
  __syncthreads();
  const float M = fmaxf(fmaxf(red[0], red[1]), fmaxf(red[2], red[3]));
  float lsum = 0.f;
  for (int it = 0; it < 7; ++it) {
    int n = it * 256 + tid;
    if (n < NSP) { float e = __expf(slg[n] - M); slg[n] = e; lsum += e; }
  }
#pragma unroll
  for (int off = 32; off >= 1; off >>= 1) lsum += __shfl_xor(lsum, off);
  if (lane == 0) red[4 + wid] = lsum;
  __syncthreads();
  const float inv = 1.0f / (red[4] + red[5] + red[6] + red[7]);
  float sh[8];
#pragma unroll
  for (int o = 0; o < 8; o++) sh[o] = 0.f;
  const int aoff = (b * NJ + j) * NSP;
  for (int it = 0; it < 7; ++it) {
    int n = it * 256 + tid;
    if (n < NSP) {
      float a = slg[n] * inv;
      A_out[aoff + n] = a;
      A_bf[aoff + n] = f2bf(a);
      float xv[8];
#pragma unroll
      for (int c = 0; c < 8; c++) xv[c] = xs[c * NSP + n];
#pragma unroll
      for (int o = 0; o < 8; o++) {
        float pi = 0.f;
#pragma unroll
        for (int c = 0; c < 8; c++) pi = fmaf(wpis[o * 8 + c], xv[c], pi);
        float w = pi * a;
        weighted_bf[(size_t)((b * NJ + j) * 8 + o) * NSP + n] = f2bf(w);
        sh[o] += w;
      }
    }
  }
#pragma unroll
  for (int o = 0; o < 8; o++) {
    float v = sh[o];
#pragma unroll
    for (int off = 32; off >= 1; off >>= 1) v += __shfl_xor(v, off);
    if (lane == 0) shred[wid][o] = v;
  }
  __syncthreads();
  if (tid < 8)
    shared_ws[b * NC + j * 8 + tid] = shred[0][tid] + shred[1][tid] + shred[2][tid] + shred[3][tid];
}

// ---------------- K2: barrier-free reg-resident MFMA GEMM (B from L2, P from LUT) ----------------
__global__ __launch_bounds__(256, 2) void k2(
    const float* __restrict__ limb_mean, const float* __restrict__ limb_std,
    const short* __restrict__ wbf, float* __restrict__ feat)
{
  const float SPf = 2500.0f / 11.0f;
  const float LOG2E = 1.4426950408889634f;
  __shared__ short lut[364];
  __shared__ float den_s[16 * 64];
  __shared__ __attribute__((aligned(16))) float scratch[64 * SST];  // 37888 B

  const int tid = threadIdx.x;
  const int l = blockIdx.y;
  const int m0 = blockIdx.x * 64;
  const int lane = tid & 63, wid = tid >> 6;
  const int lrow = lane & 15;
  const int lk8 = (lane >> 4) * 8;
  const int wrow = (wid & 1) * 32;   // m-strip pair owned by this wave
  const int kkb = (wid >> 1) * 32;   // K-half (n-offset within 64-tile)
  const int nbl = kkb + lk8;

  const float mean = limb_mean[l];
  const float sd = limb_std[l];
  const float invd2 = LOG2E / (20.0f * sd * sd + 0.1f);

  for (int i = tid; i < 364; i += 256) {
    float t = fmaf(SPf, sqrtf((float)i), -mean);
    lut[i] = f2bf(exp2f(-(t * invd2) * t));
  }
  __syncthreads();

  // per-lane m coordinates (2 m-rows, fixed for whole kernel)
  const int mA = m0 + wrow + lrow, mB = mA + 16;
  const int msx0 = mA / 144, r0_ = mA - msx0 * 144, msy0 = r0_ / 12, msz0 = r0_ - msy0 * 12;
  const int msx1 = mB / 144, r1_ = mB - msx1 * 144, msy1 = r1_ / 12, msz1 = r1_ - msy1 * 12;

  // per-lane global base pointers for the 9 B-fragment rows
  const int ja = d_CA[l], jb = d_CB[l];
  const short* gpc[9];
#pragma unroll
  for (int c = 0; c < 9; ++c) {
    int row = c * 16 + lrow;
    int bb = row / 18, s = row - bb * 18;
    int off;
    if (s < 8)        off = ((bb * NJ + ja) * CPJ + s) * NSP;
    else if (s < 16)  off = ((bb * NJ + jb) * CPJ + (s - 8)) * NSP;
    else if (s == 16) off = WA_OFF + (bb * NJ + ja) * NSP;
    else              off = WA_OFF + (bb * NJ + jb) * NSP;
    gpc[c] = wbf + off + nbl;
  }

  struct AF { short8 a0, a1; };
  auto genA = [&](int n0) {
    AF af;
#pragma unroll
    for (int i = 0; i < 8; ++i) {
      int n = n0 + nbl + i;
      int nx = n / 144, r = n - nx * 144, ny = r / 12, nz = r - ny * 12;
      int dx0 = msx0 - nx, dy0 = msy0 - ny, dz0 = msz0 - nz;
      af.a0[i] = lut[dx0 * dx0 + dy0 * dy0 + dz0 * dz0];
      int dx1 = msx1 - nx, dy1 = msy1 - ny, dz1 = msz1 - nz;
      af.a1[i] = lut[dx1 * dx1 + dy1 * dy1 + dz1 * dz1];
    }
    return af;
  };

  f32x4 acc0[9], acc1[9];
#pragma unroll
  for (int c = 0; c < 9; c++) { acc0[c] = (f32x4){0,0,0,0}; acc1[c] = (f32x4){0,0,0,0}; }

  // prologue: tile 0 fragments
  AF aC = genA(0);
  short8 bC[9];
#pragma unroll
  for (int c = 0; c < 9; ++c) bC[c] = *reinterpret_cast<const short8*>(gpc[c]);

#pragma unroll
  for (int nt = 0; nt < 27; ++nt) {
    AF aN;
    short8 bN[9];
    if (nt < 26) {
      const int n0n = (nt + 1) * 64;
#pragma unroll
      for (int c = 0; c < 9; ++c) bN[c] = *reinterpret_cast<const short8*>(gpc[c] + n0n);
      aN = genA(n0n);
    }
#pragma unroll
    for (int c = 0; c < 9; ++c) {
      acc0[c] = __builtin_amdgcn_mfma_f32_16x16x32_bf16(aC.a0, bC[c], acc0[c], 0, 0, 0);
      acc1[c] = __builtin_amdgcn_mfma_f32_16x16x32_bf16(aC.a1, bC[c], acc1[c], 0, 0, 0);
    }
    if (nt < 26) {
      aC = aN;
#pragma unroll
      for (int c = 0; c < 9; ++c) bC[c] = bN[c];
    }
  }

  // ---- epilogue: K-split reduce (waves 2,3 -> scratch; waves 0,1 add) ----
  const int rbase = 4 * (lane >> 4);
  if (wid >= 2) {
#pragma unroll
    for (int c = 0; c < 9; ++c) {
#pragma unroll
      for (int r = 0; r < 4; ++r) {
        scratch[(wrow + rbase + r) * SST + c * 16 + lrow] = acc0[c][r];
        scratch[(wrow + 16 + rbase + r) * SST + c * 16 + lrow] = acc1[c][r];
      }
    }
  }
  __syncthreads();
  if (wid < 2) {
#pragma unroll
    for (int c = 0; c < 9; ++c) {
#pragma unroll
      for (int r = 0; r < 4; ++r) {
        acc0[c][r] += scratch[(wrow + rbase + r) * SST + c * 16 + lrow];
        acc1[c][r] += scratch[(wrow + 16 + rbase + r) * SST + c * 16 + lrow];
      }
    }
#pragma unroll
    for (int c = 0; c < 9; ++c) {
      int col = c * 16 + lrow;
      int b = col / 18, s = col - b * 18;
      if (s >= 16) {
#pragma unroll
        for (int r = 0; r < 4; ++r) {
          den_s[(b * 2 + (s - 16)) * 64 + wrow + rbase + r] = 1.0f / acc0[c][r];
          den_s[(b * 2 + (s - 16)) * 64 + wrow + 16 + rbase + r] = 1.0f / acc1[c][r];
        }
      }
    }
  }
  __syncthreads();
  if (wid < 2) {
#pragma unroll
    for (int c = 0; c < 9; ++c) {
      int col = c * 16 + lrow;
      int b = col / 18, s = col - b * 18;
      if (s < 16) {
        int e = s >> 3, ch = s & 7;
        size_t obase = ((size_t)(b * 16 + l) * 2 + e) * (NSP * 8) + ch;
#pragma unroll
        for (int r = 0; r < 4; ++r) {
          int m1 = wrow + rbase + r, m2 = wrow + 16 + rbase + r;
          feat[obase + (size_t)(m0 + m1) * 8] = acc0[c][r] * den_s[(b * 2 + e) * 64 + m1];
          feat[obase + (size_t)(m0 + m2) * 8] = acc1[c][r] * den_s[(b * 2 + e) * 64 + m2];
        }
      }
    }
  }
}

// ---------------- K3: final conv with group substitution + x_pi add ----------------
__global__ __launch_bounds__(256) void k3(
    const float* __restrict__ x, const float* __restrict__ w_pi, const float* __restrict__ w_conv,
    const float* __restrict__ shared_ws, const float* __restrict__ feat,
    float* __restrict__ out)
{
  __shared__ float wcs[8 * NC];
  __shared__ float wpis[64];
  __shared__ float sh[NC];
  __shared__ float cts[8];
  const int tid = threadIdx.x;
  const int j0 = blockIdx.x, b = blockIdx.y;
  const int n = blockIdx.z * 256 + tid;
  for (int i = tid; i < 8 * NC; i += 256) wcs[i] = w_conv[j0 * 8 * NC + i];
  if (tid < 64) wpis[tid] = w_pi[j0 * 64 + tid];
  if (tid < NC) sh[tid] = shared_ws[b * NC + tid];
  __syncthreads();
  const int cnt = d_Gcnt[j0];
  if (tid < 8) {
    float v = 0.f;
    for (int c = 0; c < NC; c++) v = fmaf(wcs[tid * NC + c], sh[c], v);
    for (int g = 0; g < cnt; ++g) {
      int j1 = d_Gj1[j0][g];
      for (int cc = 0; cc < 8; ++cc) v -= wcs[tid * NC + j1 * 8 + cc] * sh[j1 * 8 + cc];
    }
    cts[tid] = v;
  }
  __syncthreads();
  if (n < NSP) {
    const float* xb = x + (size_t)(b * NC + j0 * 8) * NSP;
    float xv[8];
#pragma unroll
    for (int c = 0; c < 8; c++) xv[c] = xb[c * NSP + n];
    float o8[8];
#pragma unroll
    for (int o = 0; o < 8; o++) {
      float pi = 0.f;
#pragma unroll
      for (int c = 0; c < 8; c++) pi = fmaf(wpis[o * 8 + c], xv[c], pi);
      o8[o] = cts[o] + pi;
    }
    for (int g = 0; g < cnt; ++g) {
      int j1 = d_Gj1[j0][g], lim = d_Glim[j0][g], e = d_Ge[j0][g];
      const float* fb = feat + ((size_t)(b * 16 + lim) * 2 + e) * (NSP * 8) + (size_t)n * 8;
      float4 flo = *reinterpret_cast<const float4*>(fb);
      float4 fhi = *reinterpret_cast<const float4*>(fb + 4);
      float fv[8] = {flo.x, flo.y, flo.z, flo.w, fhi.x, fhi.y, fhi.z, fhi.w};
#pragma unroll
      for (int o = 0; o < 8; o++)
#pragma unroll
        for (int cc = 0; cc < 8; cc++)
          o8[o] = fmaf(wcs[o * NC + j1 * 8 + cc], fv[cc], o8[o]);
    }
#pragma unroll
    for (int o = 0; o < 8; o++)
      out[(size_t)(b * NC + j0 * 8 + o) * NSP + n] = o8[o];
  }
}

extern "C" void kernel_launch(void* const* d_in, const int* in_sizes, int n_in,
                              void* d_out, int out_size, void* d_ws, size_t ws_size,
                              hipStream_t stream) {
  const float* x         = (const float*)d_in[0];
  const float* w_pi      = (const float*)d_in[1];
  const float* w_att     = (const float*)d_in[2];
  const float* w_conv    = (const float*)d_in[3];
  const float* limb_mean = (const float*)d_in[4];
  const float* limb_std  = (const float*)d_in[5];

  float* out   = (float*)d_out;
  float* A_out = out + 1880064;            // out(8*136*1728) then A(8*17*1728)

  short* W_bf     = (short*)d_ws;                          // weighted(1,880,064) + A(235,008) bf16
  float* W_shared = (float*)((char*)d_ws + 4230144);       // 1,088 floats
  float* W_feat   = (float*)((char*)d_ws + 4234496);       // 3,538,944 floats [b][l][e][n][ch]

  hipLaunchKernelGGL(k1, dim3(NJ, NBATCH), dim3(256), 0, stream,
                     x, w_pi, w_att, A_out, W_bf + WA_OFF, W_bf, W_shared);
  hipLaunchKernelGGL(k2, dim3(27, 16), dim3(256), 0, stream,
                     limb_mean, limb_std, W_bf, W_feat);
  hipLaunchKernelGGL(k3, dim3(NJ, NBATCH, 7), dim3(256), 0, stream,
                     x, w_pi, w_conv, W_shared, W_feat, out);
}